// Round 1
// baseline (93.708 us; speedup 1.0000x reference)
//
#include <hip/hip_runtime.h>
#include <math.h>

// Problem constants (from reference setup_inputs)
#define BB 32
#define TT 2048
#define HH 1024

// Kernel 1: v[b,h] = sum_o dec[b,o] * W[o,h]   (v = dec @ W)
// grid (HH/256, BB), block 256. Coalesced over h; dec[b,o] is block-uniform.
__global__ __launch_bounds__(256)
void proj_vec_kernel(const float* __restrict__ dec,
                     const float* __restrict__ W,
                     float* __restrict__ v) {
    const int h = blockIdx.x * 256 + threadIdx.x;
    const int b = blockIdx.y;
    const float* decb = dec + b * HH;
    float acc = 0.f;
#pragma unroll 8
    for (int o = 0; o < HH; ++o) {
        acc += decb[o] * W[(size_t)o * HH + h];
    }
    v[b * HH + h] = acc;
}

// Kernel 2: energy[b,t] = enc[b,t,:] . v[b,:]
// One wave (64 lanes) per row. 1024 floats/row = 4 float4 per lane.
__global__ __launch_bounds__(256)
void energy_kernel(const float* __restrict__ enc,
                   const float* __restrict__ v,
                   float* __restrict__ energy) {
    const int wave = threadIdx.x >> 6;
    const int lane = threadIdx.x & 63;
    const int row  = blockIdx.x * 4 + wave;      // row in [0, BB*TT)
    const int b    = row >> 11;                  // row / TT
    const float4* e4 = reinterpret_cast<const float4*>(enc + (size_t)row * HH);
    const float4* v4 = reinterpret_cast<const float4*>(v + b * HH);
    float acc = 0.f;
#pragma unroll
    for (int k = 0; k < 4; ++k) {
        float4 e = e4[k * 64 + lane];
        float4 w = v4[k * 64 + lane];
        acc += e.x * w.x + e.y * w.y + e.z * w.z + e.w * w.w;
    }
#pragma unroll
    for (int off = 32; off > 0; off >>= 1) acc += __shfl_down(acc, off, 64);
    if (lane == 0) energy[row] = acc;
}

// Kernel 3: softmax over t for each b. One block (256 threads) per b.
__global__ __launch_bounds__(256)
void softmax_kernel(const float* __restrict__ energy,
                    float* __restrict__ out) {
    const int b   = blockIdx.x;
    const int tid = threadIdx.x;
    const float* e = energy + b * TT;
    float vals[8];
    float m = -INFINITY;
#pragma unroll
    for (int k = 0; k < 8; ++k) {
        vals[k] = e[tid + k * 256];
        m = fmaxf(m, vals[k]);
    }
    __shared__ float redm[4];
    __shared__ float reds[4];
#pragma unroll
    for (int off = 32; off > 0; off >>= 1) m = fmaxf(m, __shfl_xor(m, off, 64));
    if ((tid & 63) == 0) redm[tid >> 6] = m;
    __syncthreads();
    m = fmaxf(fmaxf(redm[0], redm[1]), fmaxf(redm[2], redm[3]));

    float s = 0.f;
#pragma unroll
    for (int k = 0; k < 8; ++k) {
        vals[k] = __expf(vals[k] - m);
        s += vals[k];
    }
#pragma unroll
    for (int off = 32; off > 0; off >>= 1) s += __shfl_xor(s, off, 64);
    if ((tid & 63) == 0) reds[tid >> 6] = s;
    __syncthreads();
    s = reds[0] + reds[1] + reds[2] + reds[3];
    const float inv = 1.0f / s;
#pragma unroll
    for (int k = 0; k < 8; ++k) out[b * TT + tid + k * 256] = vals[k] * inv;
}

extern "C" void kernel_launch(void* const* d_in, const int* in_sizes, int n_in,
                              void* d_out, int out_size, void* d_ws, size_t ws_size,
                              hipStream_t stream) {
    const float* dec = (const float*)d_in[0];   // [B,H]
    const float* enc = (const float*)d_in[1];   // [B,T,H]
    const float* W   = (const float*)d_in[2];   // [H,H] (row = o, col = h)
    // d_in[3] (bias) is intentionally unused: it contributes a per-b constant
    // to the energies, which softmax's shift invariance cancels exactly.
    float* out = (float*)d_out;                 // [B,T,1] f32

    float* v      = (float*)d_ws;               // BB*HH floats = 128 KiB
    float* energy = v + BB * HH;                // BB*TT floats = 256 KiB

    proj_vec_kernel<<<dim3(HH / 256, BB), 256, 0, stream>>>(dec, W, v);
    energy_kernel<<<(BB * TT) / 4, 256, 0, stream>>>(enc, v, energy);
    softmax_kernel<<<BB, 256, 0, stream>>>(energy, out);
}

// Round 2
// 58.417 us; speedup vs baseline: 1.6041x; 1.6041x over previous
//
#include <hip/hip_runtime.h>
#include <math.h>

// Problem constants (from reference setup_inputs)
#define BB 32
#define TT 2048
#define HH 1024

// Kernel 1: v[b,h] = sum_o dec[b,o] * W[o,h]   (v = dec @ W)
// grid (HH/64, BB) = (16,32) = 512 blocks; block 256 = 4 waves.
// tid = o_part*64 + h_local: each wave owns one o-quarter (256 o's) for 64 h's.
// 4 accumulators -> 64-deep chains; LDS reduce across the 4 o-parts.
__global__ __launch_bounds__(256)
void proj_vec_kernel(const float* __restrict__ dec,
                     const float* __restrict__ W,
                     float* __restrict__ v) {
    const int h_local = threadIdx.x & 63;
    const int o_part  = threadIdx.x >> 6;     // 0..3 (wave-uniform)
    const int h = blockIdx.x * 64 + h_local;
    const int b = blockIdx.y;
    const float* decb = dec + b * HH;
    const int o0 = o_part * 256;

    float a0 = 0.f, a1 = 0.f, a2 = 0.f, a3 = 0.f;
#pragma unroll 4
    for (int o = 0; o < 256; o += 4) {
        a0 += decb[o0 + o + 0] * W[(size_t)(o0 + o + 0) * HH + h];
        a1 += decb[o0 + o + 1] * W[(size_t)(o0 + o + 1) * HH + h];
        a2 += decb[o0 + o + 2] * W[(size_t)(o0 + o + 2) * HH + h];
        a3 += decb[o0 + o + 3] * W[(size_t)(o0 + o + 3) * HH + h];
    }
    __shared__ float red[4][64];
    red[o_part][h_local] = (a0 + a1) + (a2 + a3);
    __syncthreads();
    if (o_part == 0) {
        v[b * HH + h] = (red[0][h_local] + red[1][h_local]) +
                        (red[2][h_local] + red[3][h_local]);
    }
}

// Kernel 2: energy[b,t] = enc[b,t,:] . v[b,:]
// grid (64, BB) = 2048 blocks; block 256 = 4 waves; 256 waves per b.
// Each wave: hoist v[b,:] into 4 float4 registers ONCE, then stream 8
// consecutive rows (32 KB of enc) doing pure e-loads + FMA + shfl-reduce.
__global__ __launch_bounds__(256)
void energy_kernel(const float* __restrict__ enc,
                   const float* __restrict__ v,
                   float* __restrict__ energy) {
    const int wave = threadIdx.x >> 6;
    const int lane = threadIdx.x & 63;
    const int b    = blockIdx.y;
    const int wid  = blockIdx.x * 4 + wave;      // 0..255 within this b
    const int t0   = wid * 8;                    // first of 8 rows

    const float4* v4 = reinterpret_cast<const float4*>(v + b * HH);
    const float4 w0 = v4[0 * 64 + lane];
    const float4 w1 = v4[1 * 64 + lane];
    const float4 w2 = v4[2 * 64 + lane];
    const float4 w3 = v4[3 * 64 + lane];

    const float4* ebase =
        reinterpret_cast<const float4*>(enc + ((size_t)b * TT + t0) * HH);

#pragma unroll 2
    for (int r = 0; r < 8; ++r) {
        const float4* e4 = ebase + (size_t)r * (HH / 4);
        float4 e0 = e4[0 * 64 + lane];
        float4 e1 = e4[1 * 64 + lane];
        float4 e2 = e4[2 * 64 + lane];
        float4 e3 = e4[3 * 64 + lane];
        float acc = e0.x * w0.x + e0.y * w0.y + e0.z * w0.z + e0.w * w0.w;
        acc += e1.x * w1.x + e1.y * w1.y + e1.z * w1.z + e1.w * w1.w;
        acc += e2.x * w2.x + e2.y * w2.y + e2.z * w2.z + e2.w * w2.w;
        acc += e3.x * w3.x + e3.y * w3.y + e3.z * w3.z + e3.w * w3.w;
#pragma unroll
        for (int off = 32; off > 0; off >>= 1) acc += __shfl_down(acc, off, 64);
        if (lane == 0) energy[b * TT + t0 + r] = acc;
    }
}

// Kernel 3: softmax over t for each b. One block (256 threads) per b.
__global__ __launch_bounds__(256)
void softmax_kernel(const float* __restrict__ energy,
                    float* __restrict__ out) {
    const int b   = blockIdx.x;
    const int tid = threadIdx.x;
    const float* e = energy + b * TT;
    float vals[8];
    float m = -INFINITY;
#pragma unroll
    for (int k = 0; k < 8; ++k) {
        vals[k] = e[tid + k * 256];
        m = fmaxf(m, vals[k]);
    }
    __shared__ float redm[4];
    __shared__ float reds[4];
#pragma unroll
    for (int off = 32; off > 0; off >>= 1) m = fmaxf(m, __shfl_xor(m, off, 64));
    if ((tid & 63) == 0) redm[tid >> 6] = m;
    __syncthreads();
    m = fmaxf(fmaxf(redm[0], redm[1]), fmaxf(redm[2], redm[3]));

    float s = 0.f;
#pragma unroll
    for (int k = 0; k < 8; ++k) {
        vals[k] = __expf(vals[k] - m);
        s += vals[k];
    }
#pragma unroll
    for (int off = 32; off > 0; off >>= 1) s += __shfl_xor(s, off, 64);
    if ((tid & 63) == 0) reds[tid >> 6] = s;
    __syncthreads();
    s = reds[0] + reds[1] + reds[2] + reds[3];
    const float inv = 1.0f / s;
#pragma unroll
    for (int k = 0; k < 8; ++k) out[b * TT + tid + k * 256] = vals[k] * inv;
}

extern "C" void kernel_launch(void* const* d_in, const int* in_sizes, int n_in,
                              void* d_out, int out_size, void* d_ws, size_t ws_size,
                              hipStream_t stream) {
    const float* dec = (const float*)d_in[0];   // [B,H]
    const float* enc = (const float*)d_in[1];   // [B,T,H]
    const float* W   = (const float*)d_in[2];   // [H,H] (row = o, col = h)
    // d_in[3] (bias) is intentionally unused: it contributes a per-b constant
    // to the energies, which softmax's shift invariance cancels exactly.
    float* out = (float*)d_out;                 // [B,T,1] f32

    float* v      = (float*)d_ws;               // BB*HH floats = 128 KiB
    float* energy = v + BB * HH;                // BB*TT floats = 256 KiB

    proj_vec_kernel<<<dim3(HH / 64, BB), 256, 0, stream>>>(dec, W, v);
    energy_kernel<<<dim3(64, BB), 256, 0, stream>>>(enc, v, energy);
    softmax_kernel<<<BB, 256, 0, stream>>>(energy, out);
}